// Round 2
// baseline (443.157 us; speedup 1.0000x reference)
//
#include <hip/hip_runtime.h>

typedef float f32x4 __attribute__((ext_vector_type(4)));
typedef short s16x8 __attribute__((ext_vector_type(8)));

// Problem constants
#define NB_   32
#define NLC   2048
#define NLT   512
#define ND    256

__device__ __forceinline__ unsigned short f2bf(float f) {
    union { float f; unsigned int u; } v; v.f = f;
    unsigned int r = v.u + 0x7FFFu + ((v.u >> 16) & 1u);   // RNE to bf16
    return (unsigned short)(r >> 16);
}

// ---------------------------------------------------------------------------
// Prep: row squared-norms for context (B*LC rows) then target (B*LT rows).
// One wave per row; lane reads float4 (fully coalesced: 64 lanes * 16B = 1KB = row).
// ---------------------------------------------------------------------------
__global__ __launch_bounds__(256) void norms_kernel(
    const float* __restrict__ ctx, const float* __restrict__ tgt,
    float* __restrict__ norms)
{
    const int wave = threadIdx.x >> 6;
    const int lane = threadIdx.x & 63;
    const int rid = blockIdx.x * 4 + wave;   // 0 .. 81919
    const float* row;
    if (rid < NB_ * NLC) row = ctx + (size_t)rid * ND;
    else                 row = tgt + (size_t)(rid - NB_ * NLC) * ND;
    const float4 v = *(const float4*)(row + lane * 4);
    float s = v.x * v.x + v.y * v.y + v.z * v.z + v.w * v.w;
    #pragma unroll
    for (int off = 32; off >= 1; off >>= 1) s += __shfl_xor(s, off);
    if (lane == 0) norms[rid] = s;
}

// ---------------------------------------------------------------------------
// Fused kernel. Block = 256 threads = 4 waves, 128 Q-rows per block (32/wave).
// Transposed formulation:
//   S^T[n][m] = K(A) . Q(B)   (C/D: row=n, col=m)
//   O^T[d][m] = V^T(A) . W(B) (C/D: row=d, col=m)  -> float4 epilogue stores
// All LDS swizzles are in-row bijections:
//   Klds  [32][256]: col ^ ((row&7)<<3)   (row stride 256 shorts, bits 3-5 ok)
//   VTlds [256][32]: col ^ ((row&3)<<3)   (row stride 32 shorts, bits 3-4 only)
//   Wlds  [32][32] per wave: col ^ ((row&3)<<3)
// ---------------------------------------------------------------------------
__global__ __launch_bounds__(256, 2) void fused_dist_attn(
    const float* __restrict__ ctx, const float* __restrict__ tgt,
    const float* __restrict__ norms, float* __restrict__ out)
{
    __shared__ unsigned short Klds[32 * 256];    // [n_local][d], swizzled
    __shared__ unsigned short VTlds[256 * 32];   // [d][n_local], swizzled
    __shared__ unsigned short Wlds[4 * 32 * 32]; // per-wave [m_local][n_local], swizzled

    const int bid = blockIdx.x;
    const float *Q, *KV, *qn, *kn;
    int N;
    size_t outbase;
    if (bid < NB_ * 4) {                    // pass B: g2t rows (long, launch first)
        const int b = bid >> 2, mb = bid & 3;
        Q  = tgt + ((size_t)b * NLT + mb * 128) * ND;
        KV = ctx + (size_t)b * NLC * ND;
        qn = norms + NB_ * NLC + b * NLT + mb * 128;
        kn = norms + (size_t)b * NLC;
        N  = NLC;
        outbase = ((size_t)b * (NLC + NLT) + NLC + mb * 128) * ND;
    } else {                                 // pass A: g2c rows
        const int b2 = bid - NB_ * 4;
        const int b = b2 >> 4, mb = b2 & 15;
        Q  = ctx + ((size_t)b * NLC + mb * 128) * ND;
        KV = tgt + (size_t)b * NLT * ND;
        qn = norms + (size_t)b * NLC + mb * 128;
        kn = norms + NB_ * NLC + b * NLT;
        N  = NLT;
        outbase = ((size_t)b * (NLC + NLT) + mb * 128) * ND;
    }

    const int tid  = threadIdx.x;
    const int wave = tid >> 6;
    const int lane = tid & 63;
    const int lr   = lane & 15;   // frag row/col lane
    const int lq   = lane >> 4;   // k-chunk quarter

    // Q fragments (B operand of S^T) held in registers for the whole n-loop.
    // Lane holds Q[wave*32 + mf*16 + lr][kk*32 + lq*8 .. +7] as bf16x8.
    s16x8 qf[2][8];
    float q2r[2];
    #pragma unroll
    for (int mf = 0; mf < 2; ++mf) {
        const float* qrow = Q + (size_t)(wave * 32 + mf * 16 + lr) * ND;
        #pragma unroll
        for (int kk = 0; kk < 8; ++kk) {
            const float4 a = *(const float4*)(qrow + kk * 32 + lq * 8);
            const float4 c = *(const float4*)(qrow + kk * 32 + lq * 8 + 4);
            s16x8 f;
            f[0] = (short)f2bf(a.x); f[1] = (short)f2bf(a.y);
            f[2] = (short)f2bf(a.z); f[3] = (short)f2bf(a.w);
            f[4] = (short)f2bf(c.x); f[5] = (short)f2bf(c.y);
            f[6] = (short)f2bf(c.z); f[7] = (short)f2bf(c.w);
            qf[mf][kk] = f;
        }
        q2r[mf] = qn[wave * 32 + mf * 16 + lr];   // per-lane scalar (col side)
    }

    f32x4 acc[2][16];   // acc[mf][dt]: O^T tile, row d = dt*16+lq*4+j, col m = mf*16+lr
    #pragma unroll
    for (int mf = 0; mf < 2; ++mf)
        #pragma unroll
        for (int dt = 0; dt < 16; ++dt)
            acc[mf][dt] = (f32x4)(0.0f);

    for (int n0 = 0; n0 < N; n0 += 32) {
        __syncthreads();  // previous-iter LDS readers done before overwrite

        // ---- cooperative staging of 32x256 fp32 tile -> Klds (row-major bf16)
        //      and VTlds (transposed bf16). 512 4x4 micro-blocks, 2 per thread.
        #pragma unroll
        for (int i = 0; i < 2; ++i) {
            const int blk = tid + i * 256;
            const int r4 = (blk & 7) << 2;          // 0..28 (n_local)
            const int d4 = (blk >> 3) << 2;         // 0..252 (d)
            unsigned short kb[4][4];
            #pragma unroll
            for (int rr = 0; rr < 4; ++rr) {
                const float4 v = *(const float4*)(KV + (size_t)(n0 + r4 + rr) * ND + d4);
                kb[rr][0] = f2bf(v.x); kb[rr][1] = f2bf(v.y);
                kb[rr][2] = f2bf(v.z); kb[rr][3] = f2bf(v.w);
            }
            #pragma unroll
            for (int rr = 0; rr < 4; ++rr) {
                const int r = r4 + rr;
                *(ushort4*)&Klds[r * 256 + (d4 ^ ((r & 7) << 3))] =
                    make_ushort4(kb[rr][0], kb[rr][1], kb[rr][2], kb[rr][3]);
            }
            #pragma unroll
            for (int dd = 0; dd < 4; ++dd) {
                const int dr = d4 + dd;
                *(ushort4*)&VTlds[dr * 32 + (r4 ^ ((dr & 3) << 3))] =
                    make_ushort4(kb[0][dd], kb[1][dd], kb[2][dd], kb[3][dd]);
            }
        }
        // k2 for C/D rows n = n0 + ns*16 + lq*4 + j
        const float4 k2v0 = *(const float4*)(kn + n0 + lq * 4);
        const float4 k2v1 = *(const float4*)(kn + n0 + 16 + lq * 4);
        __syncthreads();

        // ---- S^T = K . Q^T  (A = K-frag from Klds, B = Q-frag regs)
        f32x4 sacc[2][2];   // [ns][mf]
        sacc[0][0] = (f32x4)(0.0f); sacc[0][1] = (f32x4)(0.0f);
        sacc[1][0] = (f32x4)(0.0f); sacc[1][1] = (f32x4)(0.0f);
        #pragma unroll
        for (int kk = 0; kk < 8; ++kk) {
            const int cs = (kk * 32 + lq * 8) ^ ((lr & 7) << 3);
            const s16x8 kf0 = *(const s16x8*)&Klds[lr * 256 + cs];
            const s16x8 kf1 = *(const s16x8*)&Klds[(16 + lr) * 256 + cs];
            sacc[0][0] = __builtin_amdgcn_mfma_f32_16x16x32_bf16(kf0, qf[0][kk], sacc[0][0], 0, 0, 0);
            sacc[0][1] = __builtin_amdgcn_mfma_f32_16x16x32_bf16(kf0, qf[1][kk], sacc[0][1], 0, 0, 0);
            sacc[1][0] = __builtin_amdgcn_mfma_f32_16x16x32_bf16(kf1, qf[0][kk], sacc[1][0], 0, 0, 0);
            sacc[1][1] = __builtin_amdgcn_mfma_f32_16x16x32_bf16(kf1, qf[1][kk], sacc[1][1], 0, 0, 0);
        }

        // ---- weights -> Wlds (row-major [m][n], b64 vector writes)
        #pragma unroll
        for (int ns = 0; ns < 2; ++ns) {
            const float4 k2 = ns ? k2v1 : k2v0;
            #pragma unroll
            for (int mf = 0; mf < 2; ++mf) {
                unsigned short w4[4];
                #pragma unroll
                for (int j = 0; j < 4; ++j) {
                    const float k2j = (j == 0) ? k2.x : (j == 1) ? k2.y : (j == 2) ? k2.z : k2.w;
                    float d2 = q2r[mf] + k2j - 2.0f * sacc[ns][mf][j];
                    d2 = d2 > 0.0f ? d2 : 0.0f;
                    const float w = __builtin_amdgcn_rcpf(1.0f + __builtin_amdgcn_sqrtf(d2));
                    w4[j] = f2bf(w);
                }
                const int row = mf * 16 + lr;                       // m_local
                const int col = (ns * 16 + lq * 4) ^ ((row & 3) << 3);
                *(ushort4*)&Wlds[wave * 1024 + row * 32 + col] =
                    make_ushort4(w4[0], w4[1], w4[2], w4[3]);
            }
        }
        // Wlds is per-wave: same-wave RAW ordering handled by compiler lgkmcnt.

        // ---- O^T += V^T(A) . W(B)
        s16x8 wfr[2];
        #pragma unroll
        for (int mf = 0; mf < 2; ++mf)
            wfr[mf] = *(const s16x8*)&Wlds[wave * 1024 + (mf * 16 + lr) * 32 +
                                           ((lq * 8) ^ ((lr & 3) << 3))];
        #pragma unroll
        for (int dt = 0; dt < 16; ++dt) {
            const int vr = dt * 16 + lr;
            const s16x8 vf = *(const s16x8*)&VTlds[vr * 32 + ((lq * 8) ^ ((lr & 3) << 3))];
            acc[0][dt] = __builtin_amdgcn_mfma_f32_16x16x32_bf16(vf, wfr[0], acc[0][dt], 0, 0, 0);
            acc[1][dt] = __builtin_amdgcn_mfma_f32_16x16x32_bf16(vf, wfr[1], acc[1][dt], 0, 0, 0);
        }
    }

    // ---- epilogue: O^T C/D -> O: out[m][d], d = dt*16+lq*4+j contiguous -> float4
    #pragma unroll
    for (int mf = 0; mf < 2; ++mf) {
        const size_t rowbase = outbase + (size_t)(wave * 32 + mf * 16 + lr) * ND;
        #pragma unroll
        for (int dt = 0; dt < 16; ++dt) {
            const f32x4 v = acc[mf][dt];
            *(float4*)(out + rowbase + dt * 16 + lq * 4) = make_float4(v[0], v[1], v[2], v[3]);
        }
    }
}

extern "C" void kernel_launch(void* const* d_in, const int* in_sizes, int n_in,
                              void* d_out, int out_size, void* d_ws, size_t ws_size,
                              hipStream_t stream) {
    const float* ctx = (const float*)d_in[0];   // [32, 2048, 256] fp32
    const float* tgt = (const float*)d_in[1];   // [32, 512, 256] fp32
    float* out = (float*)d_out;                 // [32, 2560, 256] fp32
    float* norms = (float*)d_ws;                // 81920 floats = 328 KB

    norms_kernel<<<81920 / 4, 256, 0, stream>>>(ctx, tgt, norms);
    fused_dist_attn<<<NB_ * 4 + NB_ * 16, 256, 0, stream>>>(ctx, tgt, norms, out);
}